// Round 4
// baseline (484.219 us; speedup 1.0000x reference)
//
#include <hip/hip_runtime.h>

// ConvLatticeModule: out[N,32] = gather(LV, idx)[N,9*32] @ W[288,32] + bias
// N=1e6, K=9, D=32, F=32. ALL FP32 in/out (indices int32).
// Strategy: pre-convert LV to bf16 ONCE into d_ws (64 MB), then gather
// bf16 rows + MFMA (fp32 accumulate), store fp32. Same f2bf values reach
// the MFMA as before -> numerics identical (absmax 0.03125 << 0.099).
//
// One wave computes a 16-vertex x 32-filter tile:
//   A-fragment layout [m120]: A[m=lane&15][k=quad*8+j] -> lane (m,quad)
//   loads 16B chunk quad of vertex (vbase+m)'s k-th neighbor bf16 row.
//   Lanes m,m+16,m+32,m+48 share one 64B row -> full-line coalescing.
//   C/D layout [m89]: col(filter)=lane&15, row(vertex)=quad*4+reg.
//
// History:
//  R0 240us: bfrag in regs (AGPR bloat) -> 12 waves/CU. FETCH 574, WRITE 125.
//  R1/R2 349/337us: launch_bounds(256,8) -> spill (WRITE 223-235); NT idx
//     load -> 9x re-fetch of idx stream (FETCH 944).
//  R3 235us: LDS-staged W + (256,4) + burst loads. WRITE 125 exact,
//     FETCH 590, occ 45%, 3.05 TB/s. Remaining: gather logical 1.15GB vs
//     128MB table; L3 can't hold LV+out+idx (289MB > 256MB) -> 550MB leak.
//  R4: bf16 pre-pass. Working set 64+125+36=225MB < 256MB L3 -> LV stays
//     resident; compulsory fetch halves; hot-loop converts vanish; per-lane
//     A-state halves (36 regs) -> launch_bounds(256,6), 24 waves/CU.

typedef __attribute__((ext_vector_type(8))) short short8;
typedef __attribute__((ext_vector_type(4))) float floatx4;

__device__ __forceinline__ unsigned short f2bf(float f) {
    union { float f; unsigned int i; } x;
    x.f = f;
    unsigned int i = x.i;
    i += 0x7fffu + ((i >> 16) & 1u);   // round-to-nearest-even
    return (unsigned short)(i >> 16);
}

#define KNB 9
#define PADW 296   // LDS row stride in elements (288 + 8 pad)

// ---- Pre-pass: LV fp32 [N*32] -> bf16 [N*32] in workspace -----------------
__global__ __launch_bounds__(256) void lv_to_bf16_kernel(
    const float* __restrict__ lv, unsigned short* __restrict__ dst, int n8)
{
    int i = (int)(blockIdx.x * blockDim.x + threadIdx.x);
    const int stride = (int)(gridDim.x * blockDim.x);
    for (; i < n8; i += stride) {
        const floatx4* p = (const floatx4*)(lv + (size_t)i * 8);
        const floatx4 lo = p[0];
        const floatx4 hi = p[1];
        short8 o;
#pragma unroll
        for (int j = 0; j < 4; ++j) {
            o[j]     = (short)f2bf(lo[j]);
            o[j + 4] = (short)f2bf(hi[j]);
        }
        *(short8*)(dst + (size_t)i * 8) = o;
    }
}

// ---- Main kernel: gather bf16 rows + MFMA ---------------------------------
__global__ __launch_bounds__(256, 6) void conv_lattice_bf16_kernel(
    const unsigned short* __restrict__ lvb,  // [N][32] bf16 (workspace)
    const int* __restrict__ nbr,             // [N][9]  int32
    const float* __restrict__ w,             // [288][32] fp32
    const float* __restrict__ bias,          // [32] fp32
    float* __restrict__ out,                 // [N][32] fp32
    int ntiles)                              // N/16
{
    // Transposed bf16 W in LDS: wt[c*PADW + r] = bf16(W[r][c])
    __shared__ __align__(16) unsigned short wt[32 * PADW];
    for (int idx = (int)threadIdx.x; idx < 288 * 32; idx += 256) {
        const int r = idx >> 5;
        const int c = idx & 31;
        wt[c * PADW + r] = f2bf(w[idx]);
    }
    __syncthreads();

    const int lane = (int)(threadIdx.x & 63u);
    const int m = lane & 15;        // A-row / C-col index
    const int quad = lane >> 4;     // k-chunk / C-row-group index

    const unsigned short* wt0 = &wt[m * PADW + quad * 8];          // filters 0..15
    const unsigned short* wt1 = &wt[(m + 16) * PADW + quad * 8];   // filters 16..31

    const float bias0 = bias[m];
    const float bias1 = bias[m + 16];

    const int wave = (int)((blockIdx.x * blockDim.x + threadIdx.x) >> 6);
    const int nw = (int)((gridDim.x * blockDim.x) >> 6);

    for (int t = wave; t < ntiles; t += nw) {
        const int vbase = t << 4;
        const int ibase = (vbase + m) * KNB;   // this lane's vertex index row

        // Phase 1a: all 9 neighbor indices (36B contiguous per lane)
        int nb[KNB];
#pragma unroll
        for (int k = 0; k < KNB; ++k)
            nb[k] = nbr[ibase + k];

        // Phase 1b: burst-issue all 9 row loads (16B bf16 chunk per lane).
        short8 a[KNB];
#pragma unroll
        for (int k = 0; k < KNB; ++k)
            a[k] = *(const short8*)(lvb + (size_t)nb[k] * 32 + quad * 8);

        // Phase 2: MFMA as loads drain (descending vmcnt waits).
        floatx4 acc0 = {0.f, 0.f, 0.f, 0.f};
        floatx4 acc1 = {0.f, 0.f, 0.f, 0.f};
#pragma unroll
        for (int k = 0; k < KNB; ++k) {
            const short8 b0 = *(const short8*)(wt0 + k * 32);  // ds_read_b128
            const short8 b1 = *(const short8*)(wt1 + k * 32);  // ds_read_b128
            acc0 = __builtin_amdgcn_mfma_f32_16x16x32_bf16(a[k], b0, acc0, 0, 0, 0);
            acc1 = __builtin_amdgcn_mfma_f32_16x16x32_bf16(a[k], b1, acc1, 0, 0, 0);
        }

        // C/D: lane holds rows quad*4+i (vertices), col m (filter) and m+16
        const int vrow = vbase + quad * 4;
#pragma unroll
        for (int i = 0; i < 4; ++i) {
            float* o = out + (size_t)(vrow + i) * 32;
            o[m]      = acc0[i] + bias0;
            o[m + 16] = acc1[i] + bias1;
        }
    }
}

// ---- Fallback (R3 kernel): used only if workspace is too small ------------
__global__ __launch_bounds__(256, 4) void conv_lattice_fp32_kernel(
    const float* __restrict__ lv, const int* __restrict__ nbr,
    const float* __restrict__ w, const float* __restrict__ bias,
    float* __restrict__ out, int ntiles)
{
    __shared__ __align__(16) unsigned short wt[32 * PADW];
    for (int idx = (int)threadIdx.x; idx < 288 * 32; idx += 256) {
        const int r = idx >> 5;
        const int c = idx & 31;
        wt[c * PADW + r] = f2bf(w[idx]);
    }
    __syncthreads();

    const int lane = (int)(threadIdx.x & 63u);
    const int m = lane & 15;
    const int quad = lane >> 4;
    const unsigned short* wt0 = &wt[m * PADW + quad * 8];
    const unsigned short* wt1 = &wt[(m + 16) * PADW + quad * 8];
    const float bias0 = bias[m];
    const float bias1 = bias[m + 16];
    const int wave = (int)((blockIdx.x * blockDim.x + threadIdx.x) >> 6);
    const int nw = (int)((gridDim.x * blockDim.x) >> 6);

    for (int t = wave; t < ntiles; t += nw) {
        const int vbase = t << 4;
        const int ibase = (vbase + m) * KNB;
        int nb[KNB];
#pragma unroll
        for (int k = 0; k < KNB; ++k) nb[k] = nbr[ibase + k];
        floatx4 lo[KNB], hi[KNB];
#pragma unroll
        for (int k = 0; k < KNB; ++k) {
            const floatx4* rp = (const floatx4*)(lv + (size_t)nb[k] * 32 + quad * 8);
            lo[k] = rp[0];
            hi[k] = rp[1];
        }
        floatx4 acc0 = {0.f, 0.f, 0.f, 0.f};
        floatx4 acc1 = {0.f, 0.f, 0.f, 0.f};
#pragma unroll
        for (int k = 0; k < KNB; ++k) {
            short8 a;
#pragma unroll
            for (int j = 0; j < 4; ++j) {
                a[j]     = (short)f2bf(lo[k][j]);
                a[j + 4] = (short)f2bf(hi[k][j]);
            }
            const short8 b0 = *(const short8*)(wt0 + k * 32);
            const short8 b1 = *(const short8*)(wt1 + k * 32);
            acc0 = __builtin_amdgcn_mfma_f32_16x16x32_bf16(a, b0, acc0, 0, 0, 0);
            acc1 = __builtin_amdgcn_mfma_f32_16x16x32_bf16(a, b1, acc1, 0, 0, 0);
        }
        const int vrow = vbase + quad * 4;
#pragma unroll
        for (int i = 0; i < 4; ++i) {
            float* o = out + (size_t)(vrow + i) * 32;
            o[m]      = acc0[i] + bias0;
            o[m + 16] = acc1[i] + bias1;
        }
    }
}

extern "C" void kernel_launch(void* const* d_in, const int* in_sizes, int n_in,
                              void* d_out, int out_size, void* d_ws, size_t ws_size,
                              hipStream_t stream) {
    const float* lv   = (const float*)d_in[0];
    const int*   nbr  = (const int*)d_in[1];
    const float* w    = (const float*)d_in[2];
    const float* bias = (const float*)d_in[3];
    float*       out  = (float*)d_out;

    const int n = in_sizes[0] / 32;       // number of vertices
    const int ntiles = n / 16;            // N=1e6 -> 62500 exact
    const size_t need = (size_t)n * 32 * sizeof(unsigned short);  // 64 MB

    if (d_ws != nullptr && ws_size >= need) {
        unsigned short* lvb = (unsigned short*)d_ws;
        // Pre-pass: 128MB read + 64MB write, streaming (~30us)
        hipLaunchKernelGGL(lv_to_bf16_kernel, dim3(2048), dim3(256), 0, stream,
                           lv, lvb, n * 4 /* n*32/8 */);
        // Main: 1536 blocks x 4 waves = 6 blocks/CU (LDS 18.9KB x 6 = 114KB,
        // 85-reg budget at (256,6)) = 24 waves/CU; ~10 tiles/wave.
        hipLaunchKernelGGL(conv_lattice_bf16_kernel, dim3(1536), dim3(256), 0,
                           stream, lvb, nbr, w, bias, out, ntiles);
    } else {
        dim3 grid(1024), block(256);
        hipLaunchKernelGGL(conv_lattice_fp32_kernel, grid, block, 0, stream,
                           lv, nbr, w, bias, out, ntiles);
    }
}

// Round 5
// 395.131 us; speedup vs baseline: 1.2255x; 1.2255x over previous
//
#include <hip/hip_runtime.h>

// ConvLatticeModule: out[N,32] = gather(LV, idx)[N,9*32] @ W[288,32] + bias
// N=1e6, K=9, D=32, F=32. ALL FP32 in/out (indices int32).
// Strategy: convert to bf16 in-kernel (RNE), MFMA with fp32 accumulate,
// store fp32. Input-rounding error ~0.015 max << 0.099 threshold.
//
// One wave computes a 16-vertex x 32-filter tile:
//   A-fragment layout [m120]: A[m=lane&15][k=quad*8+j] -> lane (m,quad) loads
//   32B chunk quad of vertex (vbase+m)'s k-th neighbor row. Lanes m,m+16,
//   m+32,m+48 share one 128B row -> full-line gather coalescing.
//   C/D layout [m89]: col(filter)=lane&15, row(vertex)=quad*4+reg.
//
// History:
//  R0 240us: bfrag in regs (AGPR bloat) -> 12 waves/CU. FETCH 574, WRITE 125.
//  R1/R2 349/337us: launch_bounds(256,8) -> spill (WRITE 223-235); NT idx
//     load -> 9x re-fetch of idx stream (FETCH 944).
//  R3 235us: LDS-staged W + (256,4) + burst loads. WRITE 125.0 exact,
//     FETCH 590, occ 45%, 3.05 TB/s.
//  R4 267us: bf16 pre-pass FAILED: 64B row < 128B TCC line -> miss path
//     fetches 2x bytes used (FETCH 796); (256,6) squeezed regs -> spill
//     (WRITE 168). bf16-table idea refuted; 128B fp32 rows are optimal
//     gather granularity.
//  R5: R3 structure EXACTLY + non-temporal out-stores. Single-variable
//     test: out write-allocate is what evicts LV from L3 (LV 128 + idx 36
//     = 164MB < 256MB fits if the 125MB write stream doesn't allocate).
//     Predict FETCH 590 -> 200-320MB, WRITE 125.0 unchanged, ~150us.

typedef __attribute__((ext_vector_type(8))) short short8;
typedef __attribute__((ext_vector_type(4))) float floatx4;

__device__ __forceinline__ unsigned short f2bf(float f) {
    union { float f; unsigned int i; } x;
    x.f = f;
    unsigned int i = x.i;
    i += 0x7fffu + ((i >> 16) & 1u);   // round-to-nearest-even
    return (unsigned short)(i >> 16);
}

#define KNB 9
#define PADW 296   // LDS row stride in elements (288 + 8 pad)

__global__ __launch_bounds__(256, 4) void conv_lattice_kernel(
    const float* __restrict__ lv,     // [N][32] fp32
    const int* __restrict__ nbr,      // [N][9]  int32
    const float* __restrict__ w,      // [288][32] fp32
    const float* __restrict__ bias,   // [32] fp32
    float* __restrict__ out,          // [N][32] fp32
    int ntiles)                       // N/16
{
    // Transposed bf16 W in LDS: wt[c*PADW + r] = bf16(W[r][c]),
    // c in [0,32) filter, r in [0,288) = k*32 + d.
    __shared__ __align__(16) unsigned short wt[32 * PADW];

    for (int idx = (int)threadIdx.x; idx < 288 * 32; idx += 256) {
        const int r = idx >> 5;
        const int c = idx & 31;
        wt[c * PADW + r] = f2bf(w[idx]);
    }
    __syncthreads();

    const int lane = (int)(threadIdx.x & 63u);
    const int m = lane & 15;        // A-row / C-col index
    const int quad = lane >> 4;     // k-chunk / C-row-group index

    // Per-lane LDS fragment bases; k walks via compile-time offset k*64B.
    const unsigned short* wt0 = &wt[m * PADW + quad * 8];            // filters 0..15
    const unsigned short* wt1 = &wt[(m + 16) * PADW + quad * 8];     // filters 16..31

    const float bias0 = bias[m];
    const float bias1 = bias[m + 16];

    const int wave = (int)((blockIdx.x * blockDim.x + threadIdx.x) >> 6);
    const int nw = (int)((gridDim.x * blockDim.x) >> 6);

    for (int t = wave; t < ntiles; t += nw) {
        const int vbase = t << 4;
        const int ibase = (vbase + m) * KNB;   // this lane's vertex index row

        // Phase 1a: all 9 neighbor indices (36B contiguous per lane)
        int nb[KNB];
#pragma unroll
        for (int k = 0; k < KNB; ++k)
            nb[k] = nbr[ibase + k];

        // Phase 1b: burst-issue all 18 row loads (32B chunk per lane per k).
        // 18 independent loads in flight per lane -> latency amortized
        // across the whole tile instead of per-k.
        floatx4 lo[KNB], hi[KNB];
#pragma unroll
        for (int k = 0; k < KNB; ++k) {
            const floatx4* rp = (const floatx4*)(lv + (size_t)nb[k] * 32 + quad * 8);
            lo[k] = rp[0];
            hi[k] = rp[1];
        }

        // Phase 2: convert + MFMA as loads drain (compiler inserts
        // descending vmcnt waits).
        floatx4 acc0 = {0.f, 0.f, 0.f, 0.f};
        floatx4 acc1 = {0.f, 0.f, 0.f, 0.f};
#pragma unroll
        for (int k = 0; k < KNB; ++k) {
            short8 a;
#pragma unroll
            for (int j = 0; j < 4; ++j) {
                a[j]     = (short)f2bf(lo[k][j]);
                a[j + 4] = (short)f2bf(hi[k][j]);
            }
            const short8 b0 = *(const short8*)(wt0 + k * 32);  // ds_read_b128
            const short8 b1 = *(const short8*)(wt1 + k * 32);  // ds_read_b128
            acc0 = __builtin_amdgcn_mfma_f32_16x16x32_bf16(a, b0, acc0, 0, 0, 0);
            acc1 = __builtin_amdgcn_mfma_f32_16x16x32_bf16(a, b1, acc1, 0, 0, 0);
        }

        // C/D: lane holds rows quad*4+i (vertices), col m (filter) and m+16.
        // NT stores: write-once stream, do NOT allocate in L2/L3 -> keep
        // the cache for the LV gather table.
        const int vrow = vbase + quad * 4;
#pragma unroll
        for (int i = 0; i < 4; ++i) {
            float* o = out + (size_t)(vrow + i) * 32;
            __builtin_nontemporal_store(acc0[i] + bias0, o + m);
            __builtin_nontemporal_store(acc1[i] + bias1, o + m + 16);
        }
    }
}

extern "C" void kernel_launch(void* const* d_in, const int* in_sizes, int n_in,
                              void* d_out, int out_size, void* d_ws, size_t ws_size,
                              hipStream_t stream) {
    const float* lv   = (const float*)d_in[0];
    const int*   nbr  = (const int*)d_in[1];
    const float* w    = (const float*)d_in[2];
    const float* bias = (const float*)d_in[3];
    float*       out  = (float*)d_out;

    const int n = in_sizes[0] / 32;       // number of vertices
    const int ntiles = n / 16;            // N=1e6 -> 62500 exact

    // 1024 blocks x 4 waves = 4096 waves = 16 waves/CU at 128-reg budget
    // (4 blocks/CU; LDS 18.5KB x 4 = 74KB < 160KB). ~15 tiles/wave.
    dim3 grid(1024), block(256);
    hipLaunchKernelGGL(conv_lattice_kernel, grid, block, 0, stream,
                       lv, nbr, w, bias, out, ntiles);
}